// Round 5
// baseline (96.249 us; speedup 1.0000x reference)
//
#include <hip/hip_runtime.h>

// LearnableDemosaick: B=16,H=512,W=512,K=8,f=5, fp32.
// out = is_green ? mosaick : softmax_k(sel_conv) . green_conv
// is_green = (y%2)==(x%2). Edge-clamped 5x5 cross-correlation.
//
// Round-5: round-3 analysis revisited — both LDS (45%) and VALU (53%) pipes
// half-idle => latency-bound at dx-iteration boundaries, not pipe-bound.
// One change vs round 3: fully unroll dx (straight-line 25-tap body) so the
// scheduler overlaps next-slice ds_reads under current FMA block. Filters
// stay in LDS (known-good). __launch_bounds__(256,4) bounds VGPR at 128 to
// prevent round-1-style hoisting blowup.

#define BDIM 256
#define TW 64           // tile width (pixels)
#define TH 32           // tile height (pixels)
#define LWT (TW + 4)    // 68 floats per LDS row
#define LHT (TH + 4)    // 36 rows

__global__ __launch_bounds__(BDIM, 4) void demosaick_kernel(
    const float* __restrict__ mos,   // [B,1,H,W]
    const float* __restrict__ sf,    // [5,5,8]  (dy,dx,k)
    const float* __restrict__ gf,    // [5,5,8]
    float* __restrict__ out,         // [B,1,H,W]
    int H, int W)
{
    __shared__ float tile[LHT * LWT];     // 2448 floats = 9.8 KB
    __shared__ float filt[25 * 16];       // per tap: sel[8] | grn[8]

    const int tid   = threadIdx.x;
    const int b     = blockIdx.z;
    const int tileX = blockIdx.x * TW;    // even
    const int tileY = blockIdx.y * TH;    // even
    const float* img = mos + (size_t)b * H * W;

    // stage mosaick tile + 2-halo (edge-clamped)
    for (int i = tid; i < LHT * LWT; i += BDIM) {
        int r = i / LWT;
        int c = i - r * LWT;
        int gy = min(max(tileY - 2 + r, 0), H - 1);
        int gx = min(max(tileX - 2 + c, 0), W - 1);
        tile[i] = img[(size_t)gy * W + gx];
    }
    // stage filters: filt[tap*16 + c], c<8 = sel, c>=8 = grn
    for (int i = tid; i < 400; i += BDIM) {
        int tap = i >> 4;
        int c   = i & 15;
        filt[i] = (c < 8) ? sf[tap * 8 + c] : gf[tap * 8 + (c - 8)];
    }
    __syncthreads();

    const int lane = tid & 63;        // column within tile (wave-contiguous)
    const int g    = tid >> 6;        // row group 0..3 (uniform per wave)
    const int xc   = tileX + lane;
    const int p    = xc & 1;          // column parity (tileX even -> lane&1)
    const int lx   = lane + 2;        // local col incl. halo
    const int y0   = tileY + g * 8;   // first of this thread's 8 rows (even)

    // conv pixels: y = y0 + 2r + 1 - p, r=0..3; green: y = y0 + 2r + p
    float acc[4][16];
#pragma unroll
    for (int r = 0; r < 4; ++r)
#pragma unroll
        for (int k = 0; k < 16; ++k) acc[r][k] = 0.f;

    const int rowbase = g * 8 + 1 - p;   // local row held by cache[0]

#pragma unroll
    for (int dx = 0; dx < 5; ++dx) {     // FULL unroll: straight-line body
        const int cx = lx + dx - 2;
        float cache[11];
#pragma unroll
        for (int i = 0; i < 11; ++i)
            cache[i] = tile[(rowbase + i) * LWT + cx];
#pragma unroll
        for (int dy = 0; dy < 5; ++dy) {
            const float4* fp = (const float4*)&filt[(dy * 5 + dx) * 16];
            const float4 f0 = fp[0];   // sel k=0..3
            const float4 f1 = fp[1];   // sel k=4..7
            const float4 f2 = fp[2];   // grn k=0..3
            const float4 f3 = fp[3];   // grn k=4..7
#pragma unroll
            for (int r = 0; r < 4; ++r) {
                const float v = cache[2 * r + dy];   // tap row for conv px r
                acc[r][0]  = fmaf(v, f0.x, acc[r][0]);
                acc[r][1]  = fmaf(v, f0.y, acc[r][1]);
                acc[r][2]  = fmaf(v, f0.z, acc[r][2]);
                acc[r][3]  = fmaf(v, f0.w, acc[r][3]);
                acc[r][4]  = fmaf(v, f1.x, acc[r][4]);
                acc[r][5]  = fmaf(v, f1.y, acc[r][5]);
                acc[r][6]  = fmaf(v, f1.z, acc[r][6]);
                acc[r][7]  = fmaf(v, f1.w, acc[r][7]);
                acc[r][8]  = fmaf(v, f2.x, acc[r][8]);
                acc[r][9]  = fmaf(v, f2.y, acc[r][9]);
                acc[r][10] = fmaf(v, f2.z, acc[r][10]);
                acc[r][11] = fmaf(v, f2.w, acc[r][11]);
                acc[r][12] = fmaf(v, f3.x, acc[r][12]);
                acc[r][13] = fmaf(v, f3.y, acc[r][13]);
                acc[r][14] = fmaf(v, f3.z, acc[r][14]);
                acc[r][15] = fmaf(v, f3.w, acc[r][15]);
            }
        }
    }

    const size_t ob = (size_t)b * H * W;
#pragma unroll
    for (int r = 0; r < 4; ++r) {
        float m = acc[r][0];
#pragma unroll
        for (int k = 1; k < 8; ++k) m = fmaxf(m, acc[r][k]);
        float num = 0.f, den = 0.f;
#pragma unroll
        for (int k = 0; k < 8; ++k) {
            float e = __expf(acc[r][k] - m);
            num = fmaf(e, acc[r][8 + k], num);
            den += e;
        }
        const float interp = num / den;
        const float green  = tile[(g * 8 + 2 * r + p + 2) * LWT + lx];
        out[ob + (size_t)(y0 + 2 * r + p) * W + xc]     = green;
        out[ob + (size_t)(y0 + 2 * r + 1 - p) * W + xc] = interp;
    }
}

extern "C" void kernel_launch(void* const* d_in, const int* in_sizes, int n_in,
                              void* d_out, int out_size, void* d_ws, size_t ws_size,
                              hipStream_t stream) {
    const float* mos = (const float*)d_in[0];
    const float* sf  = (const float*)d_in[1];
    const float* gf  = (const float*)d_in[2];
    float* out = (float*)d_out;

    const int H = 512, W = 512;
    const int B = in_sizes[0] / (H * W);   // 16

    dim3 grid(W / TW, H / TH, B);          // (8, 16, 16)
    dim3 block(BDIM);
    demosaick_kernel<<<grid, block, 0, stream>>>(mos, sf, gf, out, H, W);
}

// Round 6
// 92.386 us; speedup vs baseline: 1.0418x; 1.0418x over previous
//
#include <hip/hip_runtime.h>

// LearnableDemosaick: B=16,H=512,W=512,K=8,f=5, fp32.
// out = is_green ? mosaick : softmax_k(sel_conv) . green_conv
// is_green = (y%2)==(x%2). Edge-clamped 5x5 cross-correlation.
//
// Round-6: R3 counters re-fit -> VALU-issue-bound (~3540 VALU instr/wave,
// 53% busy). Lever = fewer instructions, not scheduling:
//  * v_pk_fma_f32 via ext_vector_type(2): conv FMA issue 1600 -> 800 instr.
//  * filters via wave-uniform global loads (s_load, scalar pipe) - R4's trick.
//  * dx fully unrolled (straight-line) - R5's structure.

typedef float v2f __attribute__((ext_vector_type(2)));

#define BDIM 256
#define TW 64           // tile width (pixels)
#define TH 32           // tile height (pixels)
#define LWT (TW + 4)    // 68 floats per LDS row
#define LHT (TH + 4)    // 36 rows

__global__ __launch_bounds__(BDIM, 4) void demosaick_kernel(
    const float* __restrict__ mos,   // [B,1,H,W]
    const float* __restrict__ sf,    // [5,5,8]  (dy,dx,k)
    const float* __restrict__ gf,    // [5,5,8]
    float* __restrict__ out,         // [B,1,H,W]
    int H, int W)
{
    __shared__ float tile[LHT * LWT];     // 2448 floats = 9.8 KB

    const int tid   = threadIdx.x;
    const int b     = blockIdx.z;
    const int tileX = blockIdx.x * TW;    // even
    const int tileY = blockIdx.y * TH;    // even
    const float* img = mos + (size_t)b * H * W;

    // stage mosaick tile + 2-halo (edge-clamped)
    for (int i = tid; i < LHT * LWT; i += BDIM) {
        int r = i / LWT;
        int c = i - r * LWT;
        int gy = min(max(tileY - 2 + r, 0), H - 1);
        int gx = min(max(tileX - 2 + c, 0), W - 1);
        tile[i] = img[(size_t)gy * W + gx];
    }
    __syncthreads();

    const int lane = tid & 63;        // column within tile (wave-contiguous)
    const int g    = tid >> 6;        // row group 0..3 (uniform per wave)
    const int xc   = tileX + lane;
    const int p    = xc & 1;          // column parity (tileX even -> lane&1)
    const int lx   = lane + 2;        // local col incl. halo
    const int y0   = tileY + g * 8;   // first of this thread's 8 rows (even)

    // acc[r][j]: j=0..3 sel pairs (k=2j,2j+1), j=4..7 grn pairs
    v2f acc[4][8];
#pragma unroll
    for (int r = 0; r < 4; ++r)
#pragma unroll
        for (int j = 0; j < 8; ++j) acc[r][j] = (v2f)(0.f);

    const int rowbase = g * 8 + 1 - p;   // local row held by cache[0]

#pragma unroll
    for (int dx = 0; dx < 5; ++dx) {     // straight-line 25-tap body
        const int cx = lx + dx - 2;
        float cache[11];
#pragma unroll
        for (int i = 0; i < 11; ++i)
            cache[i] = tile[(rowbase + i) * LWT + cx];
#pragma unroll
        for (int dy = 0; dy < 5; ++dy) {
            // wave-uniform, read-only -> s_load (scalar pipe, no VALU/LDS)
            const float* fsp = sf + (dy * 5 + dx) * 8;
            const float* fgp = gf + (dy * 5 + dx) * 8;
            v2f f[8];
            f[0] = *(const v2f*)(fsp);
            f[1] = *(const v2f*)(fsp + 2);
            f[2] = *(const v2f*)(fsp + 4);
            f[3] = *(const v2f*)(fsp + 6);
            f[4] = *(const v2f*)(fgp);
            f[5] = *(const v2f*)(fgp + 2);
            f[6] = *(const v2f*)(fgp + 4);
            f[7] = *(const v2f*)(fgp + 6);
#pragma unroll
            for (int r = 0; r < 4; ++r) {
                const float v = cache[2 * r + dy];   // tap row for conv px r
                const v2f vv = { v, v };
#pragma unroll
                for (int j = 0; j < 8; ++j)
                    acc[r][j] = __builtin_elementwise_fma(vv, f[j], acc[r][j]);
            }
        }
    }

    const size_t ob = (size_t)b * H * W;
#pragma unroll
    for (int r = 0; r < 4; ++r) {
        float s[8], gr[8];
#pragma unroll
        for (int j = 0; j < 4; ++j) {
            s[2 * j]      = acc[r][j].x;
            s[2 * j + 1]  = acc[r][j].y;
            gr[2 * j]     = acc[r][4 + j].x;
            gr[2 * j + 1] = acc[r][4 + j].y;
        }
        float m = s[0];
#pragma unroll
        for (int k = 1; k < 8; ++k) m = fmaxf(m, s[k]);
        float num = 0.f, den = 0.f;
#pragma unroll
        for (int k = 0; k < 8; ++k) {
            float e = __expf(s[k] - m);
            num = fmaf(e, gr[k], num);
            den += e;
        }
        const float interp = num / den;
        const float green  = tile[(g * 8 + 2 * r + p + 2) * LWT + lx];
        out[ob + (size_t)(y0 + 2 * r + p) * W + xc]     = green;
        out[ob + (size_t)(y0 + 2 * r + 1 - p) * W + xc] = interp;
    }
}

extern "C" void kernel_launch(void* const* d_in, const int* in_sizes, int n_in,
                              void* d_out, int out_size, void* d_ws, size_t ws_size,
                              hipStream_t stream) {
    const float* mos = (const float*)d_in[0];
    const float* sf  = (const float*)d_in[1];
    const float* gf  = (const float*)d_in[2];
    float* out = (float*)d_out;

    const int H = 512, W = 512;
    const int B = in_sizes[0] / (H * W);   // 16

    dim3 grid(W / TW, H / TH, B);          // (8, 16, 16)
    dim3 block(BDIM);
    demosaick_kernel<<<grid, block, 0, stream>>>(mos, sf, gf, out, H, W);
}